// Round 13
// baseline (279.447 us; speedup 1.0000x reference)
//
#include <hip/hip_runtime.h>
#include <math.h>

#define N_NODES 50000
#define N_HEDGE 5000
#define N_EDGES 400000
#define NB 2
#define NC 64
#define NEG 0.2f
#define NROWS (N_NODES * NB)   // 100000

#define GEMM_BLOCKS 1563       // (NROWS+63)/64
#define COUNT_BLOCKS 1563      // (N_EDGES+255)/256
#define SCAT_BLOCKS 1563
#define HEDGE_BLOCKS 1250      // (N_HEDGE+3)/4

__device__ __forceinline__ unsigned short f2bf(float f) {
    unsigned int u = __float_as_uint(f);
    unsigned int r = (u + 0x7FFFu + ((u >> 16) & 1u)) >> 16;   // RNE
    return (unsigned short)r;
}

// ---------------- fused GEMM (blocks 0..1562) + count/bounds (blocks 1563..3125)
__global__ __launch_bounds__(256, 4) void gemm_count_kernel(const float* __restrict__ x,
                                                            const float* __restrict__ W,
                                                            const float* __restrict__ att,
                                                            unsigned short* __restrict__ xwb,
                                                            float* __restrict__ p1,
                                                            float* __restrict__ p2,
                                                            const int* __restrict__ node_idx,
                                                            const int* __restrict__ hedge_idx,
                                                            int* __restrict__ cnt,
                                                            int* __restrict__ estart)
{
    __shared__ float xs[64 * 68];
    __shared__ float Ws[64 * 68];
    int t = threadIdx.x;

    if (blockIdx.x >= GEMM_BLOCKS) {
        // ---- count node degrees + hyperedge lower bounds
        int i = (blockIdx.x - GEMM_BLOCKS) * 256 + t;
        if (i < N_EDGES) atomicAdd(&cnt[node_idx[i]], 1);
        if (i <= N_HEDGE) {
            int lo = 0, hi = N_EDGES;
            while (lo < hi) {
                int mid = (lo + hi) >> 1;
                if (hedge_idx[mid] < i) lo = mid + 1; else hi = mid;
            }
            estart[i] = lo;
        }
        return;
    }

    int R = blockIdx.x * 64;
#pragma unroll
    for (int i = 0; i < 4; i++) {
        int lin = t + 256 * i;
        int r = lin >> 4, c4 = lin & 15;
        float4 wv = ((const float4*)W)[lin];
        *(float4*)&Ws[r * 68 + c4 * 4] = wv;
        int g = R + r;
        float4 xv = make_float4(0.f, 0.f, 0.f, 0.f);
        if (g < NROWS) {
            int n = g >> 1, b = g & 1;
            xv = ((const float4*)(x + ((size_t)b * N_NODES + n) * NC))[c4];
        }
        *(float4*)&xs[r * 68 + c4 * 4] = xv;
    }
    __syncthreads();

    int tr = t >> 4, tc = t & 15;
    float acc[4][4];
#pragma unroll
    for (int i = 0; i < 4; i++)
#pragma unroll
        for (int j = 0; j < 4; j++) acc[i][j] = 0.f;

#pragma unroll 4
    for (int k4 = 0; k4 < 16; k4++) {
        float4 xv[4], wv[4];
#pragma unroll
        for (int i = 0; i < 4; i++)
            xv[i] = *(const float4*)&xs[(tr * 4 + i) * 68 + k4 * 4];
#pragma unroll
        for (int kk = 0; kk < 4; kk++)
            wv[kk] = *(const float4*)&Ws[(k4 * 4 + kk) * 68 + tc * 4];
#pragma unroll
        for (int i = 0; i < 4; i++) {
            acc[i][0] = fmaf(xv[i].x, wv[0].x, acc[i][0]);
            acc[i][1] = fmaf(xv[i].x, wv[0].y, acc[i][1]);
            acc[i][2] = fmaf(xv[i].x, wv[0].z, acc[i][2]);
            acc[i][3] = fmaf(xv[i].x, wv[0].w, acc[i][3]);
            acc[i][0] = fmaf(xv[i].y, wv[1].x, acc[i][0]);
            acc[i][1] = fmaf(xv[i].y, wv[1].y, acc[i][1]);
            acc[i][2] = fmaf(xv[i].y, wv[1].z, acc[i][2]);
            acc[i][3] = fmaf(xv[i].y, wv[1].w, acc[i][3]);
            acc[i][0] = fmaf(xv[i].z, wv[2].x, acc[i][0]);
            acc[i][1] = fmaf(xv[i].z, wv[2].y, acc[i][1]);
            acc[i][2] = fmaf(xv[i].z, wv[2].z, acc[i][2]);
            acc[i][3] = fmaf(xv[i].z, wv[2].w, acc[i][3]);
            acc[i][0] = fmaf(xv[i].w, wv[3].x, acc[i][0]);
            acc[i][1] = fmaf(xv[i].w, wv[3].y, acc[i][1]);
            acc[i][2] = fmaf(xv[i].w, wv[3].z, acc[i][2]);
            acc[i][3] = fmaf(xv[i].w, wv[3].w, acc[i][3]);
        }
    }

    float a1x = att[tc * 4], a1y = att[tc * 4 + 1], a1z = att[tc * 4 + 2], a1w = att[tc * 4 + 3];
    float a2x = att[64 + tc * 4], a2y = att[64 + tc * 4 + 1], a2z = att[64 + tc * 4 + 2], a2w = att[64 + tc * 4 + 3];
#pragma unroll
    for (int i = 0; i < 4; i++) {
        int g = R + tr * 4 + i;
        if (g < NROWS) {
            ushort4 bv;
            bv.x = f2bf(acc[i][0]); bv.y = f2bf(acc[i][1]);
            bv.z = f2bf(acc[i][2]); bv.w = f2bf(acc[i][3]);
            ((ushort4*)(xwb + (size_t)g * 64))[tc] = bv;
        }
        float v1 = acc[i][0] * a1x + acc[i][1] * a1y + acc[i][2] * a1z + acc[i][3] * a1w;
        float v2 = acc[i][0] * a2x + acc[i][1] * a2y + acc[i][2] * a2z + acc[i][3] * a2w;
#pragma unroll
        for (int off = 8; off >= 1; off >>= 1) {
            v1 += __shfl_xor(v1, off, 64);
            v2 += __shfl_xor(v2, off, 64);
        }
        if (tc == 0 && g < NROWS) { p1[g] = v1; p2[g] = v2; }
    }
}

// ---------------- single-block scan: chunk sums -> LDS scan -> chunk prefixes
__global__ __launch_bounds__(1024) void scan_kernel(const int* __restrict__ cnt,
                                                    int* __restrict__ nstart)
{
    __shared__ int sm[1024];
    const int CH = 49;                      // ceil(50000/1024)
    int tid = threadIdx.x;
    int lo = tid * CH, hi = lo + CH;
    if (hi > N_NODES) hi = N_NODES;
    int sum = 0;
    for (int i = lo; i < hi; i++) sum += cnt[i];
    sm[tid] = sum;
    __syncthreads();
    for (int off = 1; off < 1024; off <<= 1) {
        int v = (tid >= off) ? sm[tid - off] : 0;
        __syncthreads();
        sm[tid] += v;
        __syncthreads();
    }
    if (tid == 1023) nstart[N_NODES] = sm[1023];
    int run = sm[tid] - sum;                // exclusive prefix of this chunk
    for (int i = lo; i < hi; i++) { nstart[i] = run; run += cnt[i]; }
}

// ---------------- fused scatter (blocks 0..1562) + hedge s2 (blocks 1563..2812)
__global__ __launch_bounds__(256) void scatter_hedge_kernel(const int* __restrict__ node_idx,
                                                            const int* __restrict__ hedge_idx,
                                                            const int* __restrict__ nstart,
                                                            int* __restrict__ cursor,
                                                            int* __restrict__ hperm,
                                                            int* __restrict__ pos,
                                                            const float* __restrict__ p2,
                                                            const int* __restrict__ estart,
                                                            float* __restrict__ s2)
{
    int t = threadIdx.x;
    if (blockIdx.x < SCAT_BLOCKS) {
        int e = blockIdx.x * 256 + t;
        if (e >= N_EDGES) return;
        int n = node_idx[e];
        int p = nstart[n] + atomicAdd(&cursor[n], 1);
        hperm[p] = hedge_idx[e];
        pos[e] = p;
        return;
    }
    int wv = (blockIdx.x - SCAT_BLOCKS) * 4 + (t >> 6);
    if (wv >= N_HEDGE) return;
    int lane = t & 63;
    int s = estart[wv], e1 = estart[wv + 1];
    float a0 = 0.f, a1 = 0.f;
    for (int e = s + lane; e < e1; e += 64) {
        int n = node_idx[e];
        float2 p = ((const float2*)p2)[n];
        a0 += p.x; a1 += p.y;
    }
#pragma unroll
    for (int off = 32; off >= 1; off >>= 1) {
        a0 += __shfl_xor(a0, off, 64);
        a1 += __shfl_xor(a1, off, 64);
    }
    if (lane == 0) {
        s2[wv * 2] = a0;
        s2[wv * 2 + 1] = a1;
    }
}

// ---------------- fused logits + leaky relu + per-node softmax (CSR order, in place)
__global__ void softmax_kernel(const int* __restrict__ nstart,
                               const int* __restrict__ hperm,
                               const float* __restrict__ p1,
                               const float* __restrict__ s2,
                               float* __restrict__ acsr)
{
    int n = blockIdx.x * blockDim.x + threadIdx.x;
    if (n >= N_NODES) return;
    int s = nstart[n], e1 = nstart[n + 1];
    if (s == e1) return;
    float pn0 = p1[n * 2], pn1 = p1[n * 2 + 1];
    float2* a = (float2*)acsr;
    const float2* s2v = (const float2*)s2;
    float mx0 = -INFINITY, mx1 = -INFINITY;
    for (int j = s; j < e1; j++) {
        int h = hperm[j];
        float2 sv = s2v[h];
        float r0 = pn0 + sv.x; r0 = (r0 >= 0.f) ? r0 : NEG * r0;
        float r1 = pn1 + sv.y; r1 = (r1 >= 0.f) ? r1 : NEG * r1;
        a[j] = make_float2(r0, r1);
        mx0 = fmaxf(mx0, r0); mx1 = fmaxf(mx1, r1);
    }
    float s0 = 0.f, s1 = 0.f;
    for (int j = s; j < e1; j++) {
        float2 v = a[j];
        float e0 = expf(v.x - mx0), e1f = expf(v.y - mx1);
        a[j] = make_float2(e0, e1f);
        s0 += e0; s1 += e1f;
    }
    float i0 = 1.0f / s0, i1 = 1.0f / s1;
    for (int j = s; j < e1; j++) {
        float2 v = a[j];
        a[j] = make_float2(v.x * i0, v.y * i1);
    }
}

// ---------------- pass 1: m (bf16) = (1/deg) * sum alpha * xw ; 2-wave split + LDS combine
__global__ __launch_bounds__(128) void m_kernel(const unsigned short* __restrict__ xwb,
                                                const int* __restrict__ node_idx,
                                                const int* __restrict__ estart,
                                                const int* __restrict__ pos,
                                                const float* __restrict__ acsr,
                                                unsigned short* __restrict__ mb)
{
    __shared__ float red[128];
    int h = blockIdx.x;
    int t = threadIdx.x;
    int w = t >> 6, l = t & 63;
    int b = l >> 5;                       // channel 2l: b = (2l)>>6
    int s = estart[h], e1 = estart[h + 1];
    float ax = 0.f, ay = 0.f;
    int e = s + w;
    for (; e + 6 < e1; e += 8) {
        int n0 = node_idx[e],     n1 = node_idx[e + 2];
        int n2 = node_idx[e + 4], n3 = node_idx[e + 6];
        int q0 = pos[e],     q1 = pos[e + 2];
        int q2 = pos[e + 4], q3 = pos[e + 6];
        float a0 = acsr[q0 * 2 + b], a1 = acsr[q1 * 2 + b];
        float a2 = acsr[q2 * 2 + b], a3 = acsr[q3 * 2 + b];
        unsigned int u0 = *(const unsigned int*)&xwb[(size_t)n0 * 128 + 2 * l];
        unsigned int u1 = *(const unsigned int*)&xwb[(size_t)n1 * 128 + 2 * l];
        unsigned int u2 = *(const unsigned int*)&xwb[(size_t)n2 * 128 + 2 * l];
        unsigned int u3 = *(const unsigned int*)&xwb[(size_t)n3 * 128 + 2 * l];
        ax = fmaf(a0, __uint_as_float(u0 << 16), ax);
        ay = fmaf(a0, __uint_as_float(u0 & 0xffff0000u), ay);
        ax = fmaf(a1, __uint_as_float(u1 << 16), ax);
        ay = fmaf(a1, __uint_as_float(u1 & 0xffff0000u), ay);
        ax = fmaf(a2, __uint_as_float(u2 << 16), ax);
        ay = fmaf(a2, __uint_as_float(u2 & 0xffff0000u), ay);
        ax = fmaf(a3, __uint_as_float(u3 << 16), ax);
        ay = fmaf(a3, __uint_as_float(u3 & 0xffff0000u), ay);
    }
    for (; e < e1; e += 2) {
        int n = node_idx[e];
        float a0 = acsr[pos[e] * 2 + b];
        unsigned int u = *(const unsigned int*)&xwb[(size_t)n * 128 + 2 * l];
        ax = fmaf(a0, __uint_as_float(u << 16), ax);
        ay = fmaf(a0, __uint_as_float(u & 0xffff0000u), ay);
    }
    if (w == 1) { red[2 * l] = ax; red[2 * l + 1] = ay; }
    __syncthreads();
    if (w == 0) {
        ax += red[2 * l]; ay += red[2 * l + 1];
        int d = e1 - s;
        float binv = (d > 0) ? 1.0f / (float)d : 0.0f;
        unsigned int up = (unsigned int)f2bf(binv * ax) |
                          ((unsigned int)f2bf(binv * ay) << 16);
        *(unsigned int*)&mb[(size_t)h * 128 + 2 * l] = up;
    }
}

// ---------------- pass 2: out = deg * sum alpha * m(bf16) ; 2-wave split + LDS combine
__global__ __launch_bounds__(128) void out_kernel(const unsigned short* __restrict__ mb,
                                                  const int* __restrict__ hperm,
                                                  const int* __restrict__ nstart,
                                                  const float* __restrict__ acsr,
                                                  float* __restrict__ out)
{
    __shared__ float red[128];
    int n = blockIdx.x;
    int t = threadIdx.x;
    int w = t >> 6, l = t & 63;
    int b = l >> 5;
    int s = nstart[n], e1 = nstart[n + 1];
    float ax = 0.f, ay = 0.f;
    int j = s + w;
    for (; j + 6 < e1; j += 8) {
        int h0 = hperm[j],     h1 = hperm[j + 2];
        int h2 = hperm[j + 4], h3 = hperm[j + 6];
        float a0 = acsr[j * 2 + b],       a1 = acsr[(j + 2) * 2 + b];
        float a2 = acsr[(j + 4) * 2 + b], a3 = acsr[(j + 6) * 2 + b];
        unsigned int u0 = *(const unsigned int*)&mb[(size_t)h0 * 128 + 2 * l];
        unsigned int u1 = *(const unsigned int*)&mb[(size_t)h1 * 128 + 2 * l];
        unsigned int u2 = *(const unsigned int*)&mb[(size_t)h2 * 128 + 2 * l];
        unsigned int u3 = *(const unsigned int*)&mb[(size_t)h3 * 128 + 2 * l];
        ax = fmaf(a0, __uint_as_float(u0 << 16), ax);
        ay = fmaf(a0, __uint_as_float(u0 & 0xffff0000u), ay);
        ax = fmaf(a1, __uint_as_float(u1 << 16), ax);
        ay = fmaf(a1, __uint_as_float(u1 & 0xffff0000u), ay);
        ax = fmaf(a2, __uint_as_float(u2 << 16), ax);
        ay = fmaf(a2, __uint_as_float(u2 & 0xffff0000u), ay);
        ax = fmaf(a3, __uint_as_float(u3 << 16), ax);
        ay = fmaf(a3, __uint_as_float(u3 & 0xffff0000u), ay);
    }
    for (; j < e1; j += 2) {
        int h = hperm[j];
        float a0 = acsr[j * 2 + b];
        unsigned int u = *(const unsigned int*)&mb[(size_t)h * 128 + 2 * l];
        ax = fmaf(a0, __uint_as_float(u << 16), ax);
        ay = fmaf(a0, __uint_as_float(u & 0xffff0000u), ay);
    }
    if (w == 1) { red[2 * l] = ax; red[2 * l + 1] = ay; }
    __syncthreads();
    if (w == 0) {
        ax += red[2 * l]; ay += red[2 * l + 1];
        float deg = (float)(e1 - s);
        int c = (2 * l) & 63;
        float* dst = out + (size_t)b * N_NODES * 64 + (size_t)n * 64 + c;
        __builtin_nontemporal_store(deg * ax, dst);
        __builtin_nontemporal_store(deg * ay, dst + 1);
    }
}

extern "C" void kernel_launch(void* const* d_in, const int* in_sizes, int n_in,
                              void* d_out, int out_size, void* d_ws, size_t ws_size,
                              hipStream_t stream)
{
    const float* x      = (const float*)d_in[0];
    const float* W      = (const float*)d_in[1];
    const float* att    = (const float*)d_in[2];
    const int* node_idx = (const int*)d_in[3];
    const int* hedge_idx= (const int*)d_in[4];
    float* out = (float*)d_out;

    // workspace layout — ~22MB total
    unsigned short* xwb = (unsigned short*)d_ws;        // 6,400,000 ushort (12.8MB)
    float* p1     = (float*)(xwb + (size_t)NROWS * NC); // 100,000
    float* p2     = p1 + NROWS;                         // 100,000
    float* s2     = p2 + NROWS;                         // 10,000
    float* acsr   = s2 + 10000;                         // 800,000
    unsigned short* mb = (unsigned short*)(acsr + 2 * N_EDGES); // 640,000 ushort (1.28MB)
    int* estart  = (int*)(mb + 640000);                 // 5,008 (padded)
    int* cnt     = estart + 5008;                       // 50,000
    int* cursor  = cnt + N_NODES;                       // 50,000 (contiguous with cnt)
    int* nstart  = cursor + N_NODES;                    // 50,008 (padded)
    int* hperm   = nstart + 50008;                      // 400,000
    int* pos     = hperm + N_EDGES;                     // 400,000

    hipMemsetAsync(cnt, 0, (size_t)2 * N_NODES * sizeof(int), stream);

    gemm_count_kernel<<<GEMM_BLOCKS + COUNT_BLOCKS, 256, 0, stream>>>(
        x, W, att, xwb, p1, p2, node_idx, hedge_idx, cnt, estart);
    scan_kernel<<<1, 1024, 0, stream>>>(cnt, nstart);
    scatter_hedge_kernel<<<SCAT_BLOCKS + HEDGE_BLOCKS, 256, 0, stream>>>(
        node_idx, hedge_idx, nstart, cursor, hperm, pos, p2, estart, s2);
    softmax_kernel<<<(N_NODES + 255) / 256, 256, 0, stream>>>(nstart, hperm, p1, s2, acsr);
    m_kernel<<<N_HEDGE, 128, 0, stream>>>(xwb, node_idx, estart, pos, acsr, mb);
    out_kernel<<<N_NODES, 128, 0, stream>>>(mb, hperm, nstart, acsr, out);
}